// Round 10
// baseline (307.470 us; speedup 1.0000x reference)
//
#include <hip/hip_runtime.h>
#include <hip/hip_fp16.h>

// out = h@Wd1 + (softmax(h@M@e^T)@e)@W2,  M=Wq@Wk^T, W2=Wv@Wd2 (folded on device).
// Round-10: SPLIT for block-level phase stagger (2 co-resident blocks/CU each):
//  G1: [T|O1] = H @ Mt2  (2048 blocks x 512thr, BM=32, n-half per block,
//      32KB H panel, pair-rolling global B prefetch, 1 barrier, no setprio).
//      T written f16 swizzle-baked to ws; O1 written f16 plain.
//  K2: stage-T(32KB, wave-private rows) -> softmax+u (enc streaming overlapped
//      with co-resident block's MFMA) -> out = O1 + U@W2 (1024 blocks x 512thr).
// ws: Mt2 1MB + W2t 0.5MB + Tws 32MB + O1ws 32MB = 65.5MB.

#define B_TOT   16384
#define TQn     2
#define TKn     5
#define THREADS 512

typedef _Float16 f16;
typedef _Float16 f16x8 __attribute__((ext_vector_type(8)));
typedef _Float16 f16x4 __attribute__((ext_vector_type(4)));
typedef _Float16 f16x2 __attribute__((ext_vector_type(2)));
typedef float    f32x4 __attribute__((ext_vector_type(4)));

#define MFMA16(a,b,c) __builtin_amdgcn_mfma_f32_16x16x32_f16(a, b, c, 0, 0, 0)

// ---------------- G1: [T|O1] = H @ Mt2 ----------------
__global__ __launch_bounds__(THREADS, 4) void gemm1(
    const float* __restrict__ hptr, const f16* __restrict__ Mt2,
    f16* __restrict__ Tws, f16* __restrict__ O1ws)
{
  __shared__ char smem[32768];          // 32 rows x 1024B (H panel, f16 swizzled)
  const int tid  = threadIdx.x;
  const int lane = tid & 63;
  const int w    = tid >> 6;            // wave 0..7
  const int g    = lane >> 4;
  const int l15  = lane & 15;
  const int xsw  = (l15 & 7) << 4;
  const int hb   = blockIdx.x & 1;      // n-half: 0 -> T cols, 1 -> O1 cols
  const int m0   = (blockIdx.x >> 1) * 32;
  const int n0   = w * 64;              // within-half col base (4 n-frags)

  // stage H rows m0..m0+31 (fp32 -> f16, swizzled)
  #pragma unroll
  for (int i = 0; i < 8; ++i) {
    int c   = tid + THREADS * i;        // 4096 float4 chunks
    int row = c >> 7;
    int k4  = c & 127;
    int m   = m0 + row;
    int tq  = m & 1;
    int b   = m >> 1;
    float4 v = *reinterpret_cast<const float4*>(
        hptr + ((size_t)(tq * B_TOT + b) << 9) + (k4 << 2));
    f16x4 p;
    p[0] = (f16)v.x; p[1] = (f16)v.y; p[2] = (f16)v.z; p[3] = (f16)v.w;
    *reinterpret_cast<f16x4*>(smem + row * 1024 + ((k4 << 3) ^ ((row & 7) << 4))) = p;
  }

  const f16* bsrc = Mt2 + (size_t)(hb * 512) * 512;
  #define BLD(fn, kt) (*reinterpret_cast<const f16x8*>( \
      bsrc + (size_t)(n0 + ((fn) << 4) + l15) * 512 + (kt) * 32 + (g << 3)))

  f16x8 p0 = BLD(0, 0), p1 = BLD(1, 0);   // issue before barrier
  __syncthreads();   // H staged

  f32x4 acc[2][4];
  #pragma unroll
  for (int fm = 0; fm < 2; ++fm)
    #pragma unroll
    for (int fn = 0; fn < 4; ++fn)
      acc[fm][fn] = (f32x4){0.f, 0.f, 0.f, 0.f};

  for (int kt = 0; kt < 16; ++kt) {
    f16x8 af0 = *reinterpret_cast<const f16x8*>(
        smem + l15 * 1024 + (((kt << 6) + (g << 4)) ^ xsw));
    f16x8 af1 = *reinterpret_cast<const f16x8*>(
        smem + (16 + l15) * 1024 + (((kt << 6) + (g << 4)) ^ xsw));
    f16x8 q0 = BLD(2, kt), q1 = BLD(3, kt);
    acc[0][0] = MFMA16(af0, p0, acc[0][0]);
    acc[1][0] = MFMA16(af1, p0, acc[1][0]);
    acc[0][1] = MFMA16(af0, p1, acc[0][1]);
    acc[1][1] = MFMA16(af1, p1, acc[1][1]);
    if (kt < 15) { p0 = BLD(0, kt + 1); p1 = BLD(1, kt + 1); }
    acc[0][2] = MFMA16(af0, q0, acc[0][2]);
    acc[1][2] = MFMA16(af1, q0, acc[1][2]);
    acc[0][3] = MFMA16(af0, q1, acc[0][3]);
    acc[1][3] = MFMA16(af1, q1, acc[1][3]);
  }
  #undef BLD

  // epilogue: C/D map row=(lane>>4)*4+reg, col=lane&15
  #pragma unroll
  for (int fm = 0; fm < 2; ++fm)
    #pragma unroll
    for (int fn = 0; fn < 4; ++fn)
      #pragma unroll
      for (int r = 0; r < 4; ++r) {
        int row = (fm << 4) + (g << 2) + r;
        int m   = m0 + row;
        int col = n0 + (fn << 4) + l15;
        if (hb == 0) {
          // T: f16, swizzle-baked rows of 1KB (chunk16B ^ ((m&7)<<4))
          size_t byte = (size_t)m * 1024 +
                        ((((col >> 3) << 4) ^ ((m & 7) << 4)) + ((col & 7) << 1));
          *reinterpret_cast<f16*>(reinterpret_cast<char*>(Tws) + byte) =
              (f16)acc[fm][fn][r];
        } else {
          O1ws[(size_t)m * 512 + col] = (f16)acc[fm][fn][r];
        }
      }
}

// ---------------- K2: softmax + out = O1 + U@W2 ----------------
__global__ __launch_bounds__(THREADS, 4) void attn2(
    const float* __restrict__ eptr, const f16* __restrict__ Tws,
    const f16* __restrict__ O1ws, const f16* __restrict__ W2t,
    float* __restrict__ outp)
{
  __shared__ char smem[32768];          // 32 rows x 1024B (T -> U panel, baked swizzle)
  const int tid  = threadIdx.x;
  const int lane = tid & 63;
  const int w    = tid >> 6;            // wave 0..7
  const int g    = lane >> 4;
  const int l15  = lane & 15;
  const int xsw  = (l15 & 7) << 4;
  const int b0   = blockIdx.x * 16;     // 16 batches, 32 rows
  const int m0   = b0 * 2;
  const int n0   = w * 64;

  // stage T (linear copy preserves baked swizzle); thread t covers bytes [t*64, t*64+64)
  // -> wave w stages exactly rows [4w, 4w+4) (its own softmax rows)
  {
    const char* src = reinterpret_cast<const char*>(Tws) + (size_t)m0 * 1024;
    #pragma unroll
    for (int i = 0; i < 4; ++i) {
      int q = tid * 64 + i * 16;
      *reinterpret_cast<uint4*>(smem + q) =
          *reinterpret_cast<const uint4*>(src + q);
    }
  }
  __syncthreads();   // (paranoia; rows are wave-private)

  // softmax + u = att@e (2 batches per wave; rows 4w..4w+3)
  #pragma unroll 1
  for (int bi = 0; bi < 2; ++bi) {
    const int bl = (w << 1) + bi;
    const int b  = b0 + bl;
    float4 e0[TKn], e1[TKn];
    #pragma unroll
    for (int j = 0; j < TKn; ++j) {
      const float4* p4 = reinterpret_cast<const float4*>(
          eptr + ((size_t)(j * B_TOT + b) << 9) + (lane << 3));
      e0[j] = p4[0];
      e1[j] = p4[1];
    }
    f16x8 evh[TKn];
    #pragma unroll
    for (int j = 0; j < TKn; ++j) {
      evh[j][0] = (f16)e0[j].x; evh[j][1] = (f16)e0[j].y;
      evh[j][2] = (f16)e0[j].z; evh[j][3] = (f16)e0[j].w;
      evh[j][4] = (f16)e1[j].x; evh[j][5] = (f16)e1[j].y;
      evh[j][6] = (f16)e1[j].z; evh[j][7] = (f16)e1[j].w;
    }
    f16x8 tvh[TQn];
    #pragma unroll
    for (int i = 0; i < TQn; ++i) {
      int row = (bl << 1) + i;
      tvh[i] = *reinterpret_cast<const f16x8*>(
          smem + row * 1024 + ((lane << 4) ^ ((row & 7) << 4)));
    }
    float s[TQn][TKn];
    #pragma unroll
    for (int i = 0; i < TQn; ++i)
      #pragma unroll
      for (int j = 0; j < TKn; ++j) {
        float a = 0.f;
        #pragma unroll
        for (int p = 0; p < 4; ++p) {
          f16x2 ta = {tvh[i][2 * p], tvh[i][2 * p + 1]};
          f16x2 ea = {evh[j][2 * p], evh[j][2 * p + 1]};
          a = __builtin_amdgcn_fdot2(ta, ea, a, false);
        }
        s[i][j] = a;
      }
    #pragma unroll
    for (int d = 1; d < 64; d <<= 1)
      #pragma unroll
      for (int i = 0; i < TQn; ++i)
        #pragma unroll
        for (int j = 0; j < TKn; ++j)
          s[i][j] += __shfl_xor(s[i][j], d, 64);
    #pragma unroll
    for (int i = 0; i < TQn; ++i) {
      float mx = s[i][0];
      #pragma unroll
      for (int j = 1; j < TKn; ++j) mx = fmaxf(mx, s[i][j]);
      float sum = 0.f;
      #pragma unroll
      for (int j = 0; j < TKn; ++j) { float e = __expf(s[i][j] - mx); s[i][j] = e; sum += e; }
      float rs = 1.0f / sum;
      int row = (bl << 1) + i;
      f16x8 uv;
      #pragma unroll
      for (int m = 0; m < 8; ++m) {
        float ua = 0.f;
        #pragma unroll
        for (int j = 0; j < TKn; ++j) ua += s[i][j] * (float)evh[j][m];
        uv[m] = (f16)(ua * rs);
      }
      *reinterpret_cast<f16x8*>(
          smem + row * 1024 + ((lane << 4) ^ ((row & 7) << 4))) = uv;
    }
  }

  // G2 B prologue (issue before barrier)
  #define WLD(fn, kt) (*reinterpret_cast<const f16x8*>( \
      W2t + (size_t)(n0 + ((fn) << 4) + l15) * 512 + (kt) * 32 + (g << 3)))
  f16x8 p0 = WLD(0, 0), p1 = WLD(1, 0);
  __syncthreads();   // all U visible

  // G2: acc = U @ W2t (K=512)
  f32x4 acc[2][4];
  #pragma unroll
  for (int fm = 0; fm < 2; ++fm)
    #pragma unroll
    for (int fn = 0; fn < 4; ++fn)
      acc[fm][fn] = (f32x4){0.f, 0.f, 0.f, 0.f};
  for (int kt = 0; kt < 16; ++kt) {
    f16x8 af0 = *reinterpret_cast<const f16x8*>(
        smem + l15 * 1024 + (((kt << 6) + (g << 4)) ^ xsw));
    f16x8 af1 = *reinterpret_cast<const f16x8*>(
        smem + (16 + l15) * 1024 + (((kt << 6) + (g << 4)) ^ xsw));
    f16x8 q0 = WLD(2, kt), q1 = WLD(3, kt);
    acc[0][0] = MFMA16(af0, p0, acc[0][0]);
    acc[1][0] = MFMA16(af1, p0, acc[1][0]);
    acc[0][1] = MFMA16(af0, p1, acc[0][1]);
    acc[1][1] = MFMA16(af1, p1, acc[1][1]);
    if (kt < 15) { p0 = WLD(0, kt + 1); p1 = WLD(1, kt + 1); }
    acc[0][2] = MFMA16(af0, q0, acc[0][2]);
    acc[1][2] = MFMA16(af1, q0, acc[1][2]);
    acc[0][3] = MFMA16(af0, q1, acc[0][3]);
    acc[1][3] = MFMA16(af1, q1, acc[1][3]);
  }
  #undef WLD

  // epilogue: out = acc + O1
  #pragma unroll
  for (int fm = 0; fm < 2; ++fm)
    #pragma unroll
    for (int fn = 0; fn < 4; ++fn)
      #pragma unroll
      for (int r = 0; r < 4; ++r) {
        int row = (fm << 4) + (g << 2) + r;
        int m   = m0 + row;
        int col = n0 + (fn << 4) + l15;
        float o1 = (float)O1ws[(size_t)m * 512 + col];
        int tq  = m & 1;
        int b   = m >> 1;
        outp[((size_t)(tq * B_TOT + b) << 9) + col] = acc[fm][fn][r] + o1;
      }
}

// ---- prep: Mt2[n][k] (n<512: (WqWk^T)^T; n>=512: Wdown[k][n-512]), W2t[n][k]=(Wv@Wd2)^T ----
__global__ __launch_bounds__(256) void prep_all(
    const float* __restrict__ Wq, const float* __restrict__ Wk,
    const float* __restrict__ Wv, const float* __restrict__ Wdown,
    f16* __restrict__ Mt2, f16* __restrict__ W2t)
{
  __shared__ float sA[32][68];
  __shared__ float sB[32][68];
  const int tid = threadIdx.x;
  const int bx  = blockIdx.x;

  if (bx < 512) {
    const bool mt  = (bx < 256);
    const int  bb  = mt ? bx : bx - 256;
    const int  n0  = (bb & 15) << 5;
    const int  k0  = (bb >> 4) << 5;
    float accv[4] = {0.f, 0.f, 0.f, 0.f};
    for (int e0 = 0; e0 < 512; e0 += 64) {
      if (mt) {
        #pragma unroll
        for (int i = 0; i < 2; ++i) {
          int c = tid + (i << 8);
          int r = c >> 4, e4 = (c & 15) << 2;
          *reinterpret_cast<float4*>(&sA[r][e4]) =
              *reinterpret_cast<const float4*>(Wq + ((k0 + r) << 9) + e0 + e4);
          *reinterpret_cast<float4*>(&sB[r][e4]) =
              *reinterpret_cast<const float4*>(Wk + ((n0 + r) << 9) + e0 + e4);
        }
      } else {
        #pragma unroll
        for (int i = 0; i < 2; ++i) {
          int c = tid + (i << 8);
          int r = c >> 4, e4 = (c & 15) << 2;
          *reinterpret_cast<float4*>(&sA[r][e4]) =
              *reinterpret_cast<const float4*>(Wv + ((k0 + r) << 9) + e0 + e4);
        }
        #pragma unroll
        for (int i = 0; i < 8; ++i) {
          int c = tid + (i << 8);
          int el = c >> 5, nl = c & 31;
          sB[nl][el] = Wdown[((512 + e0 + el) << 9) + n0 + nl];
        }
      }
      __syncthreads();
      #pragma unroll
      for (int i = 0; i < 4; ++i) {
        int o = tid + (i << 8);
        int nl = o >> 5, kl = o & 31;
        float sacc = accv[i];
        #pragma unroll
        for (int e = 0; e < 64; e += 4) {
          float4 a  = *reinterpret_cast<const float4*>(&sA[kl][e]);
          float4 bq = *reinterpret_cast<const float4*>(&sB[nl][e]);
          sacc += a.x * bq.x + a.y * bq.y + a.z * bq.z + a.w * bq.w;
        }
        accv[i] = sacc;
      }
      __syncthreads();
    }
    #pragma unroll
    for (int i = 0; i < 4; ++i) {
      int o = tid + (i << 8);
      int nl = o >> 5, kl = o & 31;
      if (mt) Mt2[((n0 + nl) << 9) + k0 + kl] = (f16)accv[i];
      else    W2t[((n0 + nl) << 9) + k0 + kl] = (f16)accv[i];
    }
  } else {
    const int bb = bx - 512;
    const int n0 = (bb & 15) << 5;
    const int k0 = (bb >> 4) << 5;
    #pragma unroll
    for (int i = 0; i < 4; ++i) {
      int c = tid + (i << 8);
      int r = c >> 5, nl = c & 31;
      sA[r][nl] = Wdown[((k0 + r) << 9) + n0 + nl];
    }
    __syncthreads();
    #pragma unroll
    for (int i = 0; i < 4; ++i) {
      int c = tid + (i << 8);
      int nl = c >> 5, kl = c & 31;
      Mt2[((512 + n0 + nl) << 9) + k0 + kl] = (f16)sA[kl][nl];
    }
  }
}

extern "C" void kernel_launch(void* const* d_in, const int* in_sizes, int n_in,
                              void* d_out, int out_size, void* d_ws, size_t ws_size,
                              hipStream_t stream) {
  const float* h   = (const float*)d_in[0];
  const float* enc = (const float*)d_in[1];
  const float* Wq  = (const float*)d_in[2];
  const float* Wk  = (const float*)d_in[3];
  const float* Wv  = (const float*)d_in[4];
  const float* Wd  = (const float*)d_in[5];
  float* out = (float*)d_out;

  f16* Mt2  = (f16*)d_ws;               // 1024 x 512 f16 = 1MB
  f16* W2t  = Mt2 + 1024 * 512;         // 512 x 512 f16  = 0.5MB
  f16* Tws  = W2t + 512 * 512;          // 32768 x 512 f16 = 32MB
  f16* O1ws = Tws + (size_t)32768 * 512; // 32768 x 512 f16 = 32MB

  prep_all<<<768, 256, 0, stream>>>(Wq, Wk, Wv, Wd, Mt2, W2t);
  gemm1<<<2048, THREADS, 0, stream>>>(h, Mt2, Tws, O1ws);
  attn2<<<1024, THREADS, 0, stream>>>(enc, Tws, O1ws, W2t, out);
}